// Round 5
// baseline (138.328 us; speedup 1.0000x reference)
//
#include <hip/hip_runtime.h>

// GCN layer: out = A_sparse @ (X @ W) + bias
// R17 = R15's K1 (verified in the 133.2us config: wt LDS staging, CHUNK 4096,
// pass1-first LPT) + R16's K2 register phase A (drops in0 12.3KB LDS
// round-trip; <=3 staging entries/thread held in VGPRs, static unroll).
// R16's K1 de-staging is reverted: B-fragments from global were a 64-lane
// 272B-stride gather per MFMA -> uncoalesced, regressed.

#define N_NODES 50000
#define N_EDGES 800000
#define D 128
#define BROWS 66               // rows per bucket
#define NBUCKET 758            // ceil(50000/66)
#define SLOT 1536              // per-bucket capacity (mean 1052, +15 sigma)
#define CHUNK 4096             // edges per pass1 block
#define EPT 16                 // CHUNK/256
#define GEMM_BLOCKS 782        // ceil(50000/64)
#define PASS1_BLOCKS 196       // ceil(800000/4096)
#define CSTRIDE 16             // gcursor padding: 16 ints = 64B per cursor

typedef short bf16x8 __attribute__((ext_vector_type(8)));
typedef float f32x4 __attribute__((ext_vector_type(4)));

__device__ inline unsigned short f2bf(float f) {   // RNE f32 -> bf16 bits
    unsigned u = __float_as_uint(f);
    unsigned r = (u + 0x7FFFu + ((u >> 16) & 1u)) >> 16;
    return (unsigned short)r;
}

__device__ inline void fma8(float* acc, uint4 v, float w) {
    acc[0] += __uint_as_float(v.x << 16) * w;
    acc[1] += __uint_as_float(v.x & 0xFFFF0000u) * w;
    acc[2] += __uint_as_float(v.y << 16) * w;
    acc[3] += __uint_as_float(v.y & 0xFFFF0000u) * w;
    acc[4] += __uint_as_float(v.z << 16) * w;
    acc[5] += __uint_as_float(v.z & 0xFFFF0000u) * w;
    acc[6] += __uint_as_float(v.w << 16) * w;
    acc[7] += __uint_as_float(v.w & 0xFFFF0000u) * w;
}

// ---- ws layout (bytes) ----
// S16:      [0, 12800000)            50000*128*2 bf16
// staging:  [12800000, +9314304)     758*1536 int2 (lrow<<16|col, bits(w))
// gcursor:  [22114304, +48512)       758 cursors, 64B apart
// WT16:     [22162816, +34816)       bf16 W^T padded [128][136]

// ---------------- K0: W^T bf16 prep + cursor zero (once) ----------------
__global__ __launch_bounds__(256) void wprep_kernel(const float* __restrict__ W,
                                                    unsigned short* __restrict__ WT,
                                                    int* __restrict__ gcursor) {
    int idx = blockIdx.x * 256 + threadIdx.x;
    if (idx < 128 * 128) {
        int k = idx >> 7, n = idx & 127;
        WT[n * 136 + k] = f2bf(W[idx]);
    }
    if (idx < NBUCKET * CSTRIDE) gcursor[idx] = 0;
}

// ---------------- K1: fused pass1 (blocks < PASS1_BLOCKS) + gemm ----------
__global__ __launch_bounds__(256) void fused_kernel(const float* __restrict__ X,
                                                    const unsigned short* __restrict__ WT,
                                                    unsigned short* __restrict__ S16,
                                                    const int* __restrict__ ei,
                                                    const float* __restrict__ ew,
                                                    int* __restrict__ gcursor,
                                                    int2* __restrict__ staging) {
    __shared__ __align__(16) char shmem[52224];
    const int t = threadIdx.x;
    const int lane = t & 63, wid = t >> 6;

    if (blockIdx.x >= PASS1_BLOCKS) {
        // ================= GEMM: S16 = bf16(X @ W) =================
        unsigned short* wt = (unsigned short*)shmem;            // [128][136]
        unsigned short* xt = (unsigned short*)(shmem + 34816);  // [64][136]
        const int row0 = (blockIdx.x - PASS1_BLOCKS) * 64;

        // stage W^T bf16: pure uint4 memcpy, conflict-free, no converts
        const uint4* WTg = (const uint4*)WT;
        uint4* wl = (uint4*)wt;
#pragma unroll
        for (int i = 0; i < 9; ++i) {
            int idx = t + 256 * i;                // 2176 uint4 total
            if (idx < 2176) wl[idx] = WTg[idx];
        }
        const float4* X4 = (const float4*)X;
#pragma unroll
        for (int i = 0; i < 8; ++i) {
            int idx4 = t + 256 * i;
            int r = idx4 >> 5, c4 = idx4 & 31;
            int gr = row0 + r;
            float4 v = make_float4(0.f, 0.f, 0.f, 0.f);
            if (gr < N_NODES) v = X4[gr * 32 + c4];
            ushort4 u = make_ushort4(f2bf(v.x), f2bf(v.y), f2bf(v.z), f2bf(v.w));
            *(ushort4*)&xt[r * 136 + c4 * 4] = u;
        }
        __syncthreads();

        const int m = lane & 15;
        const int q = lane >> 4;
        const int rbase = wid * 16;

        f32x4 acc[8];
#pragma unroll
        for (int nt = 0; nt < 8; ++nt) acc[nt] = (f32x4){0.f, 0.f, 0.f, 0.f};
#pragma unroll
        for (int ks = 0; ks < 4; ++ks) {
            bf16x8 a = *(const bf16x8*)&xt[(rbase + m) * 136 + ks * 32 + q * 8];
#pragma unroll
            for (int nt = 0; nt < 8; ++nt) {
                bf16x8 b = *(const bf16x8*)&wt[(nt * 16 + m) * 136 + ks * 32 + q * 8];
                acc[nt] = __builtin_amdgcn_mfma_f32_16x16x32_bf16(a, b, acc[nt], 0, 0, 0);
            }
        }
        __syncthreads();
#pragma unroll
        for (int nt = 0; nt < 8; ++nt) {
            int col = nt * 16 + m;
#pragma unroll
            for (int r = 0; r < 4; ++r) {
                int rl = rbase + q * 4 + r;
                xt[rl * 136 + col] = f2bf(acc[nt][r]);
            }
        }
        __syncthreads();
#pragma unroll
        for (int i = 0; i < 4; ++i) {
            int id = t + 256 * i;
            int r = id >> 4, c8 = (id & 15) * 8;
            int gr = row0 + r;
            if (gr < N_NODES)
                *(uint4*)&S16[gr * 128 + c8] = *(const uint4*)&xt[r * 136 + c8];
        }
    } else {
        // ================= PASS1: bucket multisplit (758 buckets) =========
        int* bufx            = (int*)shmem;                         // [4096] 16KB
        int* bufw            = (int*)(shmem + 16384);               // [4096] 16KB
        unsigned short* bof  = (unsigned short*)(shmem + 32768);    // [4096] 8KB
        int* hist            = (int*)(shmem + 40960);               // [768]
        int* lcur            = (int*)(shmem + 44032);               // [768]
        int* bmg             = (int*)(shmem + 47104);               // [768]
        int* wsum            = (int*)(shmem + 50176);               // [4]
        const int base = blockIdx.x * CHUNK;

        hist[t] = 0;
        hist[t + 256] = 0;
        hist[t + 512] = 0;
        __syncthreads();

        int rows[EPT];
        int bkt[EPT];
#pragma unroll
        for (int i = 0; i < EPT; ++i) {
            int e = base + t + 256 * i;
            rows[i] = (e < N_EDGES) ? ei[e] : -1;
            bkt[i] = (rows[i] >= 0) ? (rows[i] / BROWS) : -1;
            if (bkt[i] >= 0) atomicAdd(&hist[bkt[i]], 1);
        }
        __syncthreads();

        // three-phase wave-shfl exclusive scan of hist[768]
        int run = 0, exv[3], vv[3];
#pragma unroll
        for (int ph = 0; ph < 3; ++ph) {
            int v = hist[ph * 256 + t];
            vv[ph] = v;
            int incl = v;
#pragma unroll
            for (int off = 1; off < 64; off <<= 1) {
                int x = __shfl_up(incl, off, 64);
                if (lane >= off) incl += x;
            }
            if (lane == 63) wsum[wid] = incl;
            __syncthreads();
            int pre = 0, tot = 0;
#pragma unroll
            for (int w = 0; w < 4; ++w) {
                int x = wsum[w];
                if (w < wid) pre += x;
                tot += x;
            }
            exv[ph] = run + incl - v + pre;
            run += tot;
            __syncthreads();
        }
        const int total = run;
        lcur[t] = exv[0];
        lcur[t + 256] = exv[1];
        lcur[t + 512] = exv[2];
#pragma unroll
        for (int ph = 0; ph < 3; ++ph) {
            int b = ph * 256 + t;
            if (b < NBUCKET) {
                int v = vv[ph];
                if (v > 0) {
                    int gb = atomicAdd(&gcursor[b * CSTRIDE], v);
                    bmg[b] = b * SLOT + gb - exv[ph];
                }
            }
        }
        __syncthreads();

        // local reorder into bucket-contiguous LDS (SoA: 4B writes, 2-way max)
#pragma unroll
        for (int i = 0; i < EPT; ++i) {
            if (rows[i] >= 0) {
                int e = base + t + 256 * i;
                int col = ei[N_EDGES + e];
                float w = ew[e];
                int b = bkt[i];
                int lp = atomicAdd(&lcur[b], 1);
                int lrow = rows[i] - b * BROWS;     // 0..65
                bufx[lp] = (int)(((unsigned)lrow << 16) | (unsigned)col);
                bufw[lp] = __float_as_int(w);
                bof[lp] = (unsigned short)b;
            }
        }
        __syncthreads();

        // coalesced sweep: consecutive lp in same bucket -> consecutive gaddr
        for (int lp = t; lp < total; lp += 256) {
            int b = bof[lp];
            int g = bmg[b] + lp;
            if (g < (b + 1) * SLOT)
                staging[g] = make_int2(bufx[lp], bufw[lp]);   // overflow guard
        }
    }
}

// ---------------- K2: fused per-bucket sort + gather ----------------
// One 512-thread block per 66-row bucket. Phase A: staging -> registers
// (<=3 entries/thread, static unroll), int-atomic hist by local row, wave
// scan, sort from regs into in1 (no in0 LDS round-trip). Phase B: wave wv
// does rows wv, wv+8, ...; 4 subs of 16 lanes = each sub reads a full 256B
// S16 row with one dwordx4/lane; 2-deep edge pipeline; 2-round shfl_xor
// reduce; sub 0 stores 512B/row (+bias).
__global__ __launch_bounds__(512) void sortgather_kernel(const unsigned short* __restrict__ S16,
                                                         const int* __restrict__ gcursor,
                                                         const int2* __restrict__ staging,
                                                         const float* __restrict__ bias,
                                                         float* __restrict__ out) {
    __shared__ int2 in1[SLOT];              // 12288 B
    __shared__ int hist[128];               // entries >= BROWS stay 0
    __shared__ int exs[128];
    __shared__ int lcur[128];
    __shared__ int wsum[2];
    const int t = threadIdx.x;
    const int b = blockIdx.x;
    const int lane = t & 63;
    int cnt = gcursor[b * CSTRIDE];
    if (cnt > SLOT) cnt = SLOT;

    if (t < 128) hist[t] = 0;
    __syncthreads();

    // load staging into registers (static unroll => stays in VGPRs)
    int2 e0, e1, e2;
    int lr0 = -1, lr1 = -1, lr2 = -1;
    if (t < cnt) {
        e0 = staging[b * SLOT + t];
        lr0 = (int)(((unsigned)e0.x >> 16) & 127u);
        atomicAdd(&hist[lr0], 1);
    }
    if (t + 512 < cnt) {
        e1 = staging[b * SLOT + t + 512];
        lr1 = (int)(((unsigned)e1.x >> 16) & 127u);
        atomicAdd(&hist[lr1], 1);
    }
    if (t + 1024 < cnt) {
        e2 = staging[b * SLOT + t + 1024];
        lr2 = (int)(((unsigned)e2.x >> 16) & 127u);
        atomicAdd(&hist[lr2], 1);
    }
    __syncthreads();

    // scan hist[128] using threads 0..127
    int v = 0, incl = 0;
    if (t < 128) {
        v = hist[t];
        incl = v;
#pragma unroll
        for (int off = 1; off < 64; off <<= 1) {
            int x = __shfl_up(incl, off, 64);
            if (lane >= off) incl += x;
        }
        if (lane == 63) wsum[t >> 6] = incl;
    }
    __syncthreads();
    if (t < 128) {
        int pre = (t >= 64) ? wsum[0] : 0;
        int ex = incl - v + pre;
        exs[t] = ex;
        lcur[t] = ex;
    }
    __syncthreads();

    // sort payload from registers into in1 (row-contiguous)
    if (lr0 >= 0) { int p = atomicAdd(&lcur[lr0], 1); in1[p] = e0; }
    if (lr1 >= 0) { int p = atomicAdd(&lcur[lr1], 1); in1[p] = e1; }
    if (lr2 >= 0) { int p = atomicAdd(&lcur[lr2], 1); in1[p] = e2; }
    __syncthreads();

    // gather
    const int wv = t >> 6;                   // 0..7
    const int sub = lane >> 4;               // 0..3 edge sub-streams
    const int q = lane & 15;                 // owns dims q*8..q*8+7
    const uint4* S4 = (const uint4*)S16;     // row stride: 16 uint4
    const float4* bias4 = (const float4*)bias;
    const float4 b0 = bias4[q * 2];
    const float4 b1 = bias4[q * 2 + 1];

    for (int rr = wv; rr < BROWS; rr += 8) {
        const int beg = exs[rr];
        const int end = beg + hist[rr];
        float acc[8];
#pragma unroll
        for (int i = 0; i < 8; ++i) acc[i] = 0.f;

        int p = beg + sub;
        // 2-deep pipeline: two edges' loads in flight before their FMAs
        for (; p + 4 < end; p += 8) {
            int2 cw0 = in1[p];
            int2 cw1 = in1[p + 4];
            uint4 v0 = S4[(cw0.x & 0xFFFF) * 16 + q];
            uint4 v1 = S4[(cw1.x & 0xFFFF) * 16 + q];
            float w0 = __int_as_float(cw0.y);
            float w1 = __int_as_float(cw1.y);
            fma8(acc, v0, w0);
            fma8(acc, v1, w1);
        }
        if (p < end) {
            int2 cw = in1[p];
            uint4 v2 = S4[(cw.x & 0xFFFF) * 16 + q];
            float w = __int_as_float(cw.y);
            fma8(acc, v2, w);
        }
#pragma unroll
        for (int i = 0; i < 8; ++i) acc[i] += __shfl_xor(acc[i], 16, 64);
#pragma unroll
        for (int i = 0; i < 8; ++i) acc[i] += __shfl_xor(acc[i], 32, 64);

        int gr = b * BROWS + rr;
        if (sub == 0 && gr < N_NODES) {
            float4 o0 = make_float4(acc[0] + b0.x, acc[1] + b0.y,
                                    acc[2] + b0.z, acc[3] + b0.w);
            float4 o1 = make_float4(acc[4] + b1.x, acc[5] + b1.y,
                                    acc[6] + b1.z, acc[7] + b1.w);
            ((float4*)out)[gr * 32 + q * 2] = o0;
            ((float4*)out)[gr * 32 + q * 2 + 1] = o1;
        }
    }
}

extern "C" void kernel_launch(void* const* d_in, const int* in_sizes, int n_in,
                              void* d_out, int out_size, void* d_ws, size_t ws_size,
                              hipStream_t stream) {
    const float* X    = (const float*)d_in[0];
    const int*   ei   = (const int*)d_in[1];
    const float* ew   = (const float*)d_in[2];
    const float* W    = (const float*)d_in[3];
    const float* bias = (const float*)d_in[4];
    float* out = (float*)d_out;

    char* ws = (char*)d_ws;
    unsigned short* S16 = (unsigned short*)(ws);
    int2* staging = (int2*)(ws + 12800000);
    int*  gcursor = (int*)(ws + 22114304);
    unsigned short* WT16 = (unsigned short*)(ws + 22162816);

    wprep_kernel<<<64, 256, 0, stream>>>(W, WT16, gcursor);
    fused_kernel<<<GEMM_BLOCKS + PASS1_BLOCKS, 256, 0, stream>>>(X, WT16, S16, ei, ew,
                                                                 gcursor, staging);
    sortgather_kernel<<<NBUCKET, 512, 0, stream>>>(S16, gcursor, staging, bias, out);
}

// Round 6
// 137.514 us; speedup vs baseline: 1.0059x; 1.0059x over previous
//
#include <hip/hip_runtime.h>

// GCN layer: out = A_sparse @ (X @ W) + bias
// R18 = R15 backbone + two changes aimed at the fused kernel's latency bound
// (R13 counters: VALUBusy 3%, MfmaUtil 1%, Occ 15% at 3 blocks/CU):
//  1. WT retiled by wprep into MFMA-fragment order WTt[nt][ks][q][m][8] so
//     GEMM B-fragments are read straight from global/L2 as lane*16B
//     fully-coalesced 1KB wave loads (R16's de-staging done right; no wt LDS,
//     one less barrier, -70KB LDS traffic/block).
//  2. pass1 CHUNK 4096->2048: kernel-wide static LDS 52.2->29.9KB
//     => 5 blocks/CU, and grid 1173 blocks < 1280 resident slots => single
//     dispatch wave (makespan = max block time).
// K2 = R15's exact measured-best sortgather (in0-LDS phase A).

#define N_NODES 50000
#define N_EDGES 800000
#define D 128
#define BROWS 66               // rows per bucket
#define NBUCKET 758            // ceil(50000/66)
#define SLOT 1536              // per-bucket capacity (mean 1052, +15 sigma)
#define CHUNK 2048             // edges per pass1 block
#define EPT 8                  // CHUNK/256
#define GEMM_BLOCKS 782        // ceil(50000/64)
#define PASS1_BLOCKS 391       // ceil(800000/2048)
#define CSTRIDE 16             // gcursor padding: 16 ints = 64B per cursor

typedef short bf16x8 __attribute__((ext_vector_type(8)));
typedef float f32x4 __attribute__((ext_vector_type(4)));

__device__ inline unsigned short f2bf(float f) {   // RNE f32 -> bf16 bits
    unsigned u = __float_as_uint(f);
    unsigned r = (u + 0x7FFFu + ((u >> 16) & 1u)) >> 16;
    return (unsigned short)r;
}

__device__ inline void fma8(float* acc, uint4 v, float w) {
    acc[0] += __uint_as_float(v.x << 16) * w;
    acc[1] += __uint_as_float(v.x & 0xFFFF0000u) * w;
    acc[2] += __uint_as_float(v.y << 16) * w;
    acc[3] += __uint_as_float(v.y & 0xFFFF0000u) * w;
    acc[4] += __uint_as_float(v.z << 16) * w;
    acc[5] += __uint_as_float(v.z & 0xFFFF0000u) * w;
    acc[6] += __uint_as_float(v.w << 16) * w;
    acc[7] += __uint_as_float(v.w & 0xFFFF0000u) * w;
}

// ---- ws layout (bytes) ----
// S16:      [0, 12800000)            50000*128*2 bf16
// staging:  [12800000, +9314304)     758*1536 int2 (lrow<<16|col, bits(w))
// gcursor:  [22114304, +48512)       758 cursors, 64B apart
// WTt:      [22162816, +32768)       bf16 W in MFMA fragment order
//                                    [nt(8)][ks(4)][q(4)][m(16)][e(8)]

// ---------------- K0: W fragment-order bf16 prep + cursor zero ------------
__global__ __launch_bounds__(256) void wprep_kernel(const float* __restrict__ W,
                                                    unsigned short* __restrict__ WTt,
                                                    int* __restrict__ gcursor) {
    int idx = blockIdx.x * 256 + threadIdx.x;
    if (idx < 128 * 128) {
        int k = idx >> 7, n = idx & 127;          // W[k][n]
        int nt = n >> 4, m = n & 15;
        int ks = k >> 5, qq = (k & 31) >> 3, e = k & 7;
        WTt[((((nt * 4 + ks) * 4 + qq) * 16) + m) * 8 + e] = f2bf(W[idx]);
    }
    if (idx < NBUCKET * CSTRIDE) gcursor[idx] = 0;
}

// ---------------- K1: fused pass1 (blocks < PASS1_BLOCKS) + gemm ----------
__global__ __launch_bounds__(256) void fused_kernel(const float* __restrict__ X,
                                                    const unsigned short* __restrict__ WTt,
                                                    unsigned short* __restrict__ S16,
                                                    const int* __restrict__ ei,
                                                    const float* __restrict__ ew,
                                                    int* __restrict__ gcursor,
                                                    int2* __restrict__ staging) {
    __shared__ __align__(16) char shmem[29952];
    const int t = threadIdx.x;
    const int lane = t & 63, wid = t >> 6;

    if (blockIdx.x >= PASS1_BLOCKS) {
        // ================= GEMM: S16 = bf16(X @ W) =================
        unsigned short* xt = (unsigned short*)shmem;            // [64][136] 17408B
        const int row0 = (blockIdx.x - PASS1_BLOCKS) * 64;

        const float4* X4 = (const float4*)X;
#pragma unroll
        for (int i = 0; i < 8; ++i) {
            int idx4 = t + 256 * i;
            int r = idx4 >> 5, c4 = idx4 & 31;
            int gr = row0 + r;
            float4 v = make_float4(0.f, 0.f, 0.f, 0.f);
            if (gr < N_NODES) v = X4[gr * 32 + c4];
            ushort4 u = make_ushort4(f2bf(v.x), f2bf(v.y), f2bf(v.z), f2bf(v.w));
            *(ushort4*)&xt[r * 136 + c4 * 4] = u;
        }
        __syncthreads();

        const int m = lane & 15;
        const int q = lane >> 4;
        const int rbase = wid * 16;

        f32x4 acc[8];
#pragma unroll
        for (int nt = 0; nt < 8; ++nt) acc[nt] = (f32x4){0.f, 0.f, 0.f, 0.f};
#pragma unroll
        for (int ks = 0; ks < 4; ++ks) {
            bf16x8 a = *(const bf16x8*)&xt[(rbase + m) * 136 + ks * 32 + q * 8];
#pragma unroll
            for (int nt = 0; nt < 8; ++nt) {
                // B-fragment from global WTt: lane (q,m) reads offset
                // (((nt*4+ks)*4+q)*16+m)*8 -> lane*16B contiguous, one
                // coalesced 1KB wave load, L2-hot across all GEMM blocks.
                bf16x8 b = *(const bf16x8*)&WTt[(((nt * 4 + ks) * 4 + q) * 16 + m) * 8];
                acc[nt] = __builtin_amdgcn_mfma_f32_16x16x32_bf16(a, b, acc[nt], 0, 0, 0);
            }
        }
        __syncthreads();
#pragma unroll
        for (int nt = 0; nt < 8; ++nt) {
            int col = nt * 16 + m;
#pragma unroll
            for (int r = 0; r < 4; ++r) {
                int rl = rbase + q * 4 + r;
                xt[rl * 136 + col] = f2bf(acc[nt][r]);
            }
        }
        __syncthreads();
#pragma unroll
        for (int i = 0; i < 4; ++i) {
            int id = t + 256 * i;
            int r = id >> 4, c8 = (id & 15) * 8;
            int gr = row0 + r;
            if (gr < N_NODES)
                *(uint4*)&S16[gr * 128 + c8] = *(const uint4*)&xt[r * 136 + c8];
        }
    } else {
        // ================= PASS1: bucket multisplit (758 buckets) =========
        int* bufx            = (int*)shmem;                         // [2048] 8KB
        int* bufw            = (int*)(shmem + 8192);                // [2048] 8KB
        unsigned short* bof  = (unsigned short*)(shmem + 16384);    // [2048] 4KB
        int* hist            = (int*)(shmem + 20480);               // [768]
        int* lcur            = (int*)(shmem + 23552);               // [768]
        int* bmg             = (int*)(shmem + 26624);               // [768]
        int* wsum            = (int*)(shmem + 29696);               // [4]
        const int base = blockIdx.x * CHUNK;

        hist[t] = 0;
        hist[t + 256] = 0;
        hist[t + 512] = 0;
        __syncthreads();

        int rows[EPT];
        int bkt[EPT];
#pragma unroll
        for (int i = 0; i < EPT; ++i) {
            int e = base + t + 256 * i;
            rows[i] = (e < N_EDGES) ? ei[e] : -1;
            bkt[i] = (rows[i] >= 0) ? (rows[i] / BROWS) : -1;
            if (bkt[i] >= 0) atomicAdd(&hist[bkt[i]], 1);
        }
        __syncthreads();

        // three-phase wave-shfl exclusive scan of hist[768]
        int run = 0, exv[3], vv[3];
#pragma unroll
        for (int ph = 0; ph < 3; ++ph) {
            int v = hist[ph * 256 + t];
            vv[ph] = v;
            int incl = v;
#pragma unroll
            for (int off = 1; off < 64; off <<= 1) {
                int x = __shfl_up(incl, off, 64);
                if (lane >= off) incl += x;
            }
            if (lane == 63) wsum[wid] = incl;
            __syncthreads();
            int pre = 0, tot = 0;
#pragma unroll
            for (int w = 0; w < 4; ++w) {
                int x = wsum[w];
                if (w < wid) pre += x;
                tot += x;
            }
            exv[ph] = run + incl - v + pre;
            run += tot;
            __syncthreads();
        }
        const int total = run;
        lcur[t] = exv[0];
        lcur[t + 256] = exv[1];
        lcur[t + 512] = exv[2];
#pragma unroll
        for (int ph = 0; ph < 3; ++ph) {
            int b = ph * 256 + t;
            if (b < NBUCKET) {
                int v = vv[ph];
                if (v > 0) {
                    int gb = atomicAdd(&gcursor[b * CSTRIDE], v);
                    bmg[b] = b * SLOT + gb - exv[ph];
                }
            }
        }
        __syncthreads();

        // local reorder into bucket-contiguous LDS (SoA: 4B writes)
#pragma unroll
        for (int i = 0; i < EPT; ++i) {
            if (rows[i] >= 0) {
                int e = base + t + 256 * i;
                int col = ei[N_EDGES + e];
                float w = ew[e];
                int b = bkt[i];
                int lp = atomicAdd(&lcur[b], 1);
                int lrow = rows[i] - b * BROWS;     // 0..65
                bufx[lp] = (int)(((unsigned)lrow << 16) | (unsigned)col);
                bufw[lp] = __float_as_int(w);
                bof[lp] = (unsigned short)b;
            }
        }
        __syncthreads();

        // coalesced sweep: consecutive lp in same bucket -> consecutive gaddr
        for (int lp = t; lp < total; lp += 256) {
            int b = bof[lp];
            int g = bmg[b] + lp;
            if (g < (b + 1) * SLOT)
                staging[g] = make_int2(bufx[lp], bufw[lp]);   // overflow guard
        }
    }
}

// ---------------- K2: fused per-bucket sort + gather (R15 exact) ----------
__global__ __launch_bounds__(512) void sortgather_kernel(const unsigned short* __restrict__ S16,
                                                         const int* __restrict__ gcursor,
                                                         const int2* __restrict__ staging,
                                                         const float* __restrict__ bias,
                                                         float* __restrict__ out) {
    __shared__ int2 in0[SLOT];              // 12288 B
    __shared__ int2 in1[SLOT];              // 12288 B
    __shared__ int hist[128];               // entries >= BROWS stay 0
    __shared__ int exs[128];
    __shared__ int lcur[128];
    __shared__ int wsum[2];
    const int t = threadIdx.x;
    const int b = blockIdx.x;
    const int lane = t & 63;
    int cnt = gcursor[b * CSTRIDE];
    if (cnt > SLOT) cnt = SLOT;

    if (t < 128) hist[t] = 0;
    __syncthreads();

    for (int i = t; i < cnt; i += 512) {
        int2 v = staging[b * SLOT + i];
        in0[i] = v;
        atomicAdd(&hist[((unsigned)v.x >> 16) & 127u], 1);
    }
    __syncthreads();

    // scan hist[128] using threads 0..127
    int v = 0, incl = 0;
    if (t < 128) {
        v = hist[t];
        incl = v;
#pragma unroll
        for (int off = 1; off < 64; off <<= 1) {
            int x = __shfl_up(incl, off, 64);
            if (lane >= off) incl += x;
        }
        if (lane == 63) wsum[t >> 6] = incl;
    }
    __syncthreads();
    if (t < 128) {
        int pre = (t >= 64) ? wsum[0] : 0;
        int ex = incl - v + pre;
        exs[t] = ex;
        lcur[t] = ex;
    }
    __syncthreads();

    // sort payload directly into in1 (row-contiguous)
    for (int i = t; i < cnt; i += 512) {
        int2 e = in0[i];
        int lr = (int)(((unsigned)e.x >> 16) & 127u);
        int p = atomicAdd(&lcur[lr], 1);
        in1[p] = e;
    }
    __syncthreads();

    // gather
    const int wv = t >> 6;                   // 0..7
    const int sub = lane >> 4;               // 0..3 edge sub-streams
    const int q = lane & 15;                 // owns dims q*8..q*8+7
    const uint4* S4 = (const uint4*)S16;     // row stride: 16 uint4
    const float4* bias4 = (const float4*)bias;
    const float4 b0 = bias4[q * 2];
    const float4 b1 = bias4[q * 2 + 1];

    for (int rr = wv; rr < BROWS; rr += 8) {
        const int beg = exs[rr];
        const int end = beg + hist[rr];
        float acc[8];
#pragma unroll
        for (int i = 0; i < 8; ++i) acc[i] = 0.f;

        int p = beg + sub;
        // 2-deep pipeline: two edges' loads in flight before their FMAs
        for (; p + 4 < end; p += 8) {
            int2 cw0 = in1[p];
            int2 cw1 = in1[p + 4];
            uint4 v0 = S4[(cw0.x & 0xFFFF) * 16 + q];
            uint4 v1 = S4[(cw1.x & 0xFFFF) * 16 + q];
            float w0 = __int_as_float(cw0.y);
            float w1 = __int_as_float(cw1.y);
            fma8(acc, v0, w0);
            fma8(acc, v1, w1);
        }
        if (p < end) {
            int2 cw = in1[p];
            uint4 v2 = S4[(cw.x & 0xFFFF) * 16 + q];
            float w = __int_as_float(cw.y);
            fma8(acc, v2, w);
        }
#pragma unroll
        for (int i = 0; i < 8; ++i) acc[i] += __shfl_xor(acc[i], 16, 64);
#pragma unroll
        for (int i = 0; i < 8; ++i) acc[i] += __shfl_xor(acc[i], 32, 64);

        int gr = b * BROWS + rr;
        if (sub == 0 && gr < N_NODES) {
            float4 o0 = make_float4(acc[0] + b0.x, acc[1] + b0.y,
                                    acc[2] + b0.z, acc[3] + b0.w);
            float4 o1 = make_float4(acc[4] + b1.x, acc[5] + b1.y,
                                    acc[6] + b1.z, acc[7] + b1.w);
            ((float4*)out)[gr * 32 + q * 2] = o0;
            ((float4*)out)[gr * 32 + q * 2 + 1] = o1;
        }
    }
}

extern "C" void kernel_launch(void* const* d_in, const int* in_sizes, int n_in,
                              void* d_out, int out_size, void* d_ws, size_t ws_size,
                              hipStream_t stream) {
    const float* X    = (const float*)d_in[0];
    const int*   ei   = (const int*)d_in[1];
    const float* ew   = (const float*)d_in[2];
    const float* W    = (const float*)d_in[3];
    const float* bias = (const float*)d_in[4];
    float* out = (float*)d_out;

    char* ws = (char*)d_ws;
    unsigned short* S16 = (unsigned short*)(ws);
    int2* staging = (int2*)(ws + 12800000);
    int*  gcursor = (int*)(ws + 22114304);
    unsigned short* WTt = (unsigned short*)(ws + 22162816);

    wprep_kernel<<<64, 256, 0, stream>>>(W, WTt, gcursor);
    fused_kernel<<<GEMM_BLOCKS + PASS1_BLOCKS, 256, 0, stream>>>(X, WTt, S16, ei, ew,
                                                                 gcursor, staging);
    sortgather_kernel<<<NBUCKET, 512, 0, stream>>>(S16, gcursor, staging, bias, out);
}

// Round 7
// 136.251 us; speedup vs baseline: 1.0152x; 1.0093x over previous
//
#include <hip/hip_runtime.h>

// GCN layer: out = A_sparse @ (X @ W) + bias
// R19 = R15 verbatim (measured best, 133.2us) + ONE change: K2 gather
// pipeline 2-deep -> 4-deep (4 edges' int2+uint4 loads in flight before
// FMAs). deg~16 / 4 subs = ~4 edges per sub => one memory round-trip per
// row instead of two. Everything else untouched (R16/R17/R18 occupancy
// experiments on K1 all regressed vs R15; lever abandoned).

#define N_NODES 50000
#define N_EDGES 800000
#define D 128
#define BROWS 66               // rows per bucket
#define NBUCKET 758            // ceil(50000/66)
#define SLOT 1536              // per-bucket capacity (mean 1052, +15 sigma)
#define CHUNK 4096             // edges per pass1 block
#define EPT 16                 // CHUNK/256
#define GEMM_BLOCKS 782        // ceil(50000/64)
#define PASS1_BLOCKS 196       // ceil(800000/4096)
#define CSTRIDE 16             // gcursor padding: 16 ints = 64B per cursor

typedef short bf16x8 __attribute__((ext_vector_type(8)));
typedef float f32x4 __attribute__((ext_vector_type(4)));

__device__ inline unsigned short f2bf(float f) {   // RNE f32 -> bf16 bits
    unsigned u = __float_as_uint(f);
    unsigned r = (u + 0x7FFFu + ((u >> 16) & 1u)) >> 16;
    return (unsigned short)r;
}

__device__ inline void fma8(float* acc, uint4 v, float w) {
    acc[0] += __uint_as_float(v.x << 16) * w;
    acc[1] += __uint_as_float(v.x & 0xFFFF0000u) * w;
    acc[2] += __uint_as_float(v.y << 16) * w;
    acc[3] += __uint_as_float(v.y & 0xFFFF0000u) * w;
    acc[4] += __uint_as_float(v.z << 16) * w;
    acc[5] += __uint_as_float(v.z & 0xFFFF0000u) * w;
    acc[6] += __uint_as_float(v.w << 16) * w;
    acc[7] += __uint_as_float(v.w & 0xFFFF0000u) * w;
}

// ---- ws layout (bytes) ----
// S16:      [0, 12800000)            50000*128*2 bf16
// staging:  [12800000, +9314304)     758*1536 int2 (lrow<<16|col, bits(w))
// gcursor:  [22114304, +48512)       758 cursors, 64B apart
// WT16:     [22162816, +34816)       bf16 W^T padded [128][136]

// ---------------- K0: W^T bf16 prep + cursor zero (once) ----------------
__global__ __launch_bounds__(256) void wprep_kernel(const float* __restrict__ W,
                                                    unsigned short* __restrict__ WT,
                                                    int* __restrict__ gcursor) {
    int idx = blockIdx.x * 256 + threadIdx.x;
    if (idx < 128 * 128) {
        int k = idx >> 7, n = idx & 127;
        WT[n * 136 + k] = f2bf(W[idx]);
    }
    if (idx < NBUCKET * CSTRIDE) gcursor[idx] = 0;
}

// ---------------- K1: fused pass1 (blocks < PASS1_BLOCKS) + gemm ----------
__global__ __launch_bounds__(256) void fused_kernel(const float* __restrict__ X,
                                                    const unsigned short* __restrict__ WT,
                                                    unsigned short* __restrict__ S16,
                                                    const int* __restrict__ ei,
                                                    const float* __restrict__ ew,
                                                    int* __restrict__ gcursor,
                                                    int2* __restrict__ staging) {
    __shared__ __align__(16) char shmem[52224];
    const int t = threadIdx.x;
    const int lane = t & 63, wid = t >> 6;

    if (blockIdx.x >= PASS1_BLOCKS) {
        // ================= GEMM: S16 = bf16(X @ W) =================
        unsigned short* wt = (unsigned short*)shmem;            // [128][136]
        unsigned short* xt = (unsigned short*)(shmem + 34816);  // [64][136]
        const int row0 = (blockIdx.x - PASS1_BLOCKS) * 64;

        // stage W^T bf16: pure uint4 memcpy, conflict-free, no converts
        const uint4* WTg = (const uint4*)WT;
        uint4* wl = (uint4*)wt;
#pragma unroll
        for (int i = 0; i < 9; ++i) {
            int idx = t + 256 * i;                // 2176 uint4 total
            if (idx < 2176) wl[idx] = WTg[idx];
        }
        const float4* X4 = (const float4*)X;
#pragma unroll
        for (int i = 0; i < 8; ++i) {
            int idx4 = t + 256 * i;
            int r = idx4 >> 5, c4 = idx4 & 31;
            int gr = row0 + r;
            float4 v = make_float4(0.f, 0.f, 0.f, 0.f);
            if (gr < N_NODES) v = X4[gr * 32 + c4];
            ushort4 u = make_ushort4(f2bf(v.x), f2bf(v.y), f2bf(v.z), f2bf(v.w));
            *(ushort4*)&xt[r * 136 + c4 * 4] = u;
        }
        __syncthreads();

        const int m = lane & 15;
        const int q = lane >> 4;
        const int rbase = wid * 16;

        f32x4 acc[8];
#pragma unroll
        for (int nt = 0; nt < 8; ++nt) acc[nt] = (f32x4){0.f, 0.f, 0.f, 0.f};
#pragma unroll
        for (int ks = 0; ks < 4; ++ks) {
            bf16x8 a = *(const bf16x8*)&xt[(rbase + m) * 136 + ks * 32 + q * 8];
#pragma unroll
            for (int nt = 0; nt < 8; ++nt) {
                bf16x8 b = *(const bf16x8*)&wt[(nt * 16 + m) * 136 + ks * 32 + q * 8];
                acc[nt] = __builtin_amdgcn_mfma_f32_16x16x32_bf16(a, b, acc[nt], 0, 0, 0);
            }
        }
        __syncthreads();
#pragma unroll
        for (int nt = 0; nt < 8; ++nt) {
            int col = nt * 16 + m;
#pragma unroll
            for (int r = 0; r < 4; ++r) {
                int rl = rbase + q * 4 + r;
                xt[rl * 136 + col] = f2bf(acc[nt][r]);
            }
        }
        __syncthreads();
#pragma unroll
        for (int i = 0; i < 4; ++i) {
            int id = t + 256 * i;
            int r = id >> 4, c8 = (id & 15) * 8;
            int gr = row0 + r;
            if (gr < N_NODES)
                *(uint4*)&S16[gr * 128 + c8] = *(const uint4*)&xt[r * 136 + c8];
        }
    } else {
        // ================= PASS1: bucket multisplit (758 buckets) =========
        int* bufx            = (int*)shmem;                         // [4096] 16KB
        int* bufw            = (int*)(shmem + 16384);               // [4096] 16KB
        unsigned short* bof  = (unsigned short*)(shmem + 32768);    // [4096] 8KB
        int* hist            = (int*)(shmem + 40960);               // [768]
        int* lcur            = (int*)(shmem + 44032);               // [768]
        int* bmg             = (int*)(shmem + 47104);               // [768]
        int* wsum            = (int*)(shmem + 50176);               // [4]
        const int base = blockIdx.x * CHUNK;

        hist[t] = 0;
        hist[t + 256] = 0;
        hist[t + 512] = 0;
        __syncthreads();

        int rows[EPT];
        int bkt[EPT];
#pragma unroll
        for (int i = 0; i < EPT; ++i) {
            int e = base + t + 256 * i;
            rows[i] = (e < N_EDGES) ? ei[e] : -1;
            bkt[i] = (rows[i] >= 0) ? (rows[i] / BROWS) : -1;
            if (bkt[i] >= 0) atomicAdd(&hist[bkt[i]], 1);
        }
        __syncthreads();

        // three-phase wave-shfl exclusive scan of hist[768]
        int run = 0, exv[3], vv[3];
#pragma unroll
        for (int ph = 0; ph < 3; ++ph) {
            int v = hist[ph * 256 + t];
            vv[ph] = v;
            int incl = v;
#pragma unroll
            for (int off = 1; off < 64; off <<= 1) {
                int x = __shfl_up(incl, off, 64);
                if (lane >= off) incl += x;
            }
            if (lane == 63) wsum[wid] = incl;
            __syncthreads();
            int pre = 0, tot = 0;
#pragma unroll
            for (int w = 0; w < 4; ++w) {
                int x = wsum[w];
                if (w < wid) pre += x;
                tot += x;
            }
            exv[ph] = run + incl - v + pre;
            run += tot;
            __syncthreads();
        }
        const int total = run;
        lcur[t] = exv[0];
        lcur[t + 256] = exv[1];
        lcur[t + 512] = exv[2];
#pragma unroll
        for (int ph = 0; ph < 3; ++ph) {
            int b = ph * 256 + t;
            if (b < NBUCKET) {
                int v = vv[ph];
                if (v > 0) {
                    int gb = atomicAdd(&gcursor[b * CSTRIDE], v);
                    bmg[b] = b * SLOT + gb - exv[ph];
                }
            }
        }
        __syncthreads();

        // local reorder into bucket-contiguous LDS (SoA: 4B writes, 2-way max)
#pragma unroll
        for (int i = 0; i < EPT; ++i) {
            if (rows[i] >= 0) {
                int e = base + t + 256 * i;
                int col = ei[N_EDGES + e];
                float w = ew[e];
                int b = bkt[i];
                int lp = atomicAdd(&lcur[b], 1);
                int lrow = rows[i] - b * BROWS;     // 0..65
                bufx[lp] = (int)(((unsigned)lrow << 16) | (unsigned)col);
                bufw[lp] = __float_as_int(w);
                bof[lp] = (unsigned short)b;
            }
        }
        __syncthreads();

        // coalesced sweep: consecutive lp in same bucket -> consecutive gaddr
        for (int lp = t; lp < total; lp += 256) {
            int b = bof[lp];
            int g = bmg[b] + lp;
            if (g < (b + 1) * SLOT)
                staging[g] = make_int2(bufx[lp], bufw[lp]);   // overflow guard
        }
    }
}

// ---------------- K2: fused per-bucket sort + gather ----------------
// One 512-thread block per 66-row bucket. Phase A: bucket -> in0, int-atomic
// hist by local row, wave scan, sort directly into in1 (no perm indirection).
// Phase B: wave wv does rows wv, wv+8, ...; 4 subs of 16 lanes = each sub
// reads a full 256B S16 row with one dwordx4/lane; 4-deep edge pipeline
// (whole typical row in one latency round-trip); 2-round shfl_xor reduce;
// sub 0 stores 512B/row (+bias).
__global__ __launch_bounds__(512) void sortgather_kernel(const unsigned short* __restrict__ S16,
                                                         const int* __restrict__ gcursor,
                                                         const int2* __restrict__ staging,
                                                         const float* __restrict__ bias,
                                                         float* __restrict__ out) {
    __shared__ int2 in0[SLOT];              // 12288 B
    __shared__ int2 in1[SLOT];              // 12288 B
    __shared__ int hist[128];               // entries >= BROWS stay 0
    __shared__ int exs[128];
    __shared__ int lcur[128];
    __shared__ int wsum[2];
    const int t = threadIdx.x;
    const int b = blockIdx.x;
    const int lane = t & 63;
    int cnt = gcursor[b * CSTRIDE];
    if (cnt > SLOT) cnt = SLOT;

    if (t < 128) hist[t] = 0;
    __syncthreads();

    for (int i = t; i < cnt; i += 512) {
        int2 v = staging[b * SLOT + i];
        in0[i] = v;
        atomicAdd(&hist[((unsigned)v.x >> 16) & 127u], 1);
    }
    __syncthreads();

    // scan hist[128] using threads 0..127
    int v = 0, incl = 0;
    if (t < 128) {
        v = hist[t];
        incl = v;
#pragma unroll
        for (int off = 1; off < 64; off <<= 1) {
            int x = __shfl_up(incl, off, 64);
            if (lane >= off) incl += x;
        }
        if (lane == 63) wsum[t >> 6] = incl;
    }
    __syncthreads();
    if (t < 128) {
        int pre = (t >= 64) ? wsum[0] : 0;
        int ex = incl - v + pre;
        exs[t] = ex;
        lcur[t] = ex;
    }
    __syncthreads();

    // sort payload directly into in1 (row-contiguous)
    for (int i = t; i < cnt; i += 512) {
        int2 e = in0[i];
        int lr = (int)(((unsigned)e.x >> 16) & 127u);
        int p = atomicAdd(&lcur[lr], 1);
        in1[p] = e;
    }
    __syncthreads();

    // gather
    const int wv = t >> 6;                   // 0..7
    const int sub = lane >> 4;               // 0..3 edge sub-streams
    const int q = lane & 15;                 // owns dims q*8..q*8+7
    const uint4* S4 = (const uint4*)S16;     // row stride: 16 uint4
    const float4* bias4 = (const float4*)bias;
    const float4 b0 = bias4[q * 2];
    const float4 b1 = bias4[q * 2 + 1];

    for (int rr = wv; rr < BROWS; rr += 8) {
        const int beg = exs[rr];
        const int end = beg + hist[rr];
        float acc[8];
#pragma unroll
        for (int i = 0; i < 8; ++i) acc[i] = 0.f;

        int p = beg + sub;
        // 4-deep pipeline: four edges' loads in flight before their FMAs
        for (; p + 12 < end; p += 16) {
            int2 c0 = in1[p];
            int2 c1 = in1[p + 4];
            int2 c2 = in1[p + 8];
            int2 c3 = in1[p + 12];
            uint4 v0 = S4[(c0.x & 0xFFFF) * 16 + q];
            uint4 v1 = S4[(c1.x & 0xFFFF) * 16 + q];
            uint4 v2 = S4[(c2.x & 0xFFFF) * 16 + q];
            uint4 v3 = S4[(c3.x & 0xFFFF) * 16 + q];
            fma8(acc, v0, __int_as_float(c0.y));
            fma8(acc, v1, __int_as_float(c1.y));
            fma8(acc, v2, __int_as_float(c2.y));
            fma8(acc, v3, __int_as_float(c3.y));
        }
        // 2-deep remainder
        for (; p + 4 < end; p += 8) {
            int2 c0 = in1[p];
            int2 c1 = in1[p + 4];
            uint4 v0 = S4[(c0.x & 0xFFFF) * 16 + q];
            uint4 v1 = S4[(c1.x & 0xFFFF) * 16 + q];
            fma8(acc, v0, __int_as_float(c0.y));
            fma8(acc, v1, __int_as_float(c1.y));
        }
        if (p < end) {
            int2 c0 = in1[p];
            uint4 v0 = S4[(c0.x & 0xFFFF) * 16 + q];
            fma8(acc, v0, __int_as_float(c0.y));
        }
#pragma unroll
        for (int i = 0; i < 8; ++i) acc[i] += __shfl_xor(acc[i], 16, 64);
#pragma unroll
        for (int i = 0; i < 8; ++i) acc[i] += __shfl_xor(acc[i], 32, 64);

        int gr = b * BROWS + rr;
        if (sub == 0 && gr < N_NODES) {
            float4 o0 = make_float4(acc[0] + b0.x, acc[1] + b0.y,
                                    acc[2] + b0.z, acc[3] + b0.w);
            float4 o1 = make_float4(acc[4] + b1.x, acc[5] + b1.y,
                                    acc[6] + b1.z, acc[7] + b1.w);
            ((float4*)out)[gr * 32 + q * 2] = o0;
            ((float4*)out)[gr * 32 + q * 2 + 1] = o1;
        }
    }
}

extern "C" void kernel_launch(void* const* d_in, const int* in_sizes, int n_in,
                              void* d_out, int out_size, void* d_ws, size_t ws_size,
                              hipStream_t stream) {
    const float* X    = (const float*)d_in[0];
    const int*   ei   = (const int*)d_in[1];
    const float* ew   = (const float*)d_in[2];
    const float* W    = (const float*)d_in[3];
    const float* bias = (const float*)d_in[4];
    float* out = (float*)d_out;

    char* ws = (char*)d_ws;
    unsigned short* S16 = (unsigned short*)(ws);
    int2* staging = (int2*)(ws + 12800000);
    int*  gcursor = (int*)(ws + 22114304);
    unsigned short* WT16 = (unsigned short*)(ws + 22162816);

    wprep_kernel<<<64, 256, 0, stream>>>(W, WT16, gcursor);
    fused_kernel<<<GEMM_BLOCKS + PASS1_BLOCKS, 256, 0, stream>>>(X, WT16, S16, ei, ew,
                                                                 gcursor, staging);
    sortgather_kernel<<<NBUCKET, 512, 0, stream>>>(S16, gcursor, staging, bias, out);
}

// Round 8
// 132.668 us; speedup vs baseline: 1.0427x; 1.0270x over previous
//
#include <hip/hip_runtime.h>

// GCN layer: out = A_sparse @ (X @ W) + bias
// R20 = R15 algorithm exactly, but K1 at 512 threads/block: halves the
// per-block critical path (the LPT makespan floor) for both branches.
//  - pass1: EPT 16->8, 8-wave scan (phases 512+256), sweep stride 512.
//  - GEMM: 8 waves; wave pair (rbase) x nt-half h: 4 MFMA tiles/wave.
//  - occupancy: 52.2KB LDS -> 3 blocks/CU as before, but now 1536 thr/CU.
// K2 = R15 exact (2-deep; R19's 4-deep was null, lever closed).

#define N_NODES 50000
#define N_EDGES 800000
#define D 128
#define BROWS 66               // rows per bucket
#define NBUCKET 758            // ceil(50000/66)
#define SLOT 1536              // per-bucket capacity (mean 1052, +15 sigma)
#define CHUNK 4096             // edges per pass1 block
#define EPT 8                  // CHUNK/512
#define GEMM_BLOCKS 782        // ceil(50000/64)
#define PASS1_BLOCKS 196       // ceil(800000/4096)
#define CSTRIDE 16             // gcursor padding: 16 ints = 64B per cursor

typedef short bf16x8 __attribute__((ext_vector_type(8)));
typedef float f32x4 __attribute__((ext_vector_type(4)));

__device__ inline unsigned short f2bf(float f) {   // RNE f32 -> bf16 bits
    unsigned u = __float_as_uint(f);
    unsigned r = (u + 0x7FFFu + ((u >> 16) & 1u)) >> 16;
    return (unsigned short)r;
}

__device__ inline void fma8(float* acc, uint4 v, float w) {
    acc[0] += __uint_as_float(v.x << 16) * w;
    acc[1] += __uint_as_float(v.x & 0xFFFF0000u) * w;
    acc[2] += __uint_as_float(v.y << 16) * w;
    acc[3] += __uint_as_float(v.y & 0xFFFF0000u) * w;
    acc[4] += __uint_as_float(v.z << 16) * w;
    acc[5] += __uint_as_float(v.z & 0xFFFF0000u) * w;
    acc[6] += __uint_as_float(v.w << 16) * w;
    acc[7] += __uint_as_float(v.w & 0xFFFF0000u) * w;
}

// ---- ws layout (bytes) ----
// S16:      [0, 12800000)            50000*128*2 bf16
// staging:  [12800000, +9314304)     758*1536 int2 (lrow<<16|col, bits(w))
// gcursor:  [22114304, +48512)       758 cursors, 64B apart
// WT16:     [22162816, +34816)       bf16 W^T padded [128][136]

// ---------------- K0: W^T bf16 prep + cursor zero (once) ----------------
__global__ __launch_bounds__(256) void wprep_kernel(const float* __restrict__ W,
                                                    unsigned short* __restrict__ WT,
                                                    int* __restrict__ gcursor) {
    int idx = blockIdx.x * 256 + threadIdx.x;
    if (idx < 128 * 128) {
        int k = idx >> 7, n = idx & 127;
        WT[n * 136 + k] = f2bf(W[idx]);
    }
    if (idx < NBUCKET * CSTRIDE) gcursor[idx] = 0;
}

// ---------------- K1: fused pass1 (blocks < PASS1_BLOCKS) + gemm ----------
__global__ __launch_bounds__(512) void fused_kernel(const float* __restrict__ X,
                                                    const unsigned short* __restrict__ WT,
                                                    unsigned short* __restrict__ S16,
                                                    const int* __restrict__ ei,
                                                    const float* __restrict__ ew,
                                                    int* __restrict__ gcursor,
                                                    int2* __restrict__ staging) {
    __shared__ __align__(16) char shmem[52224];
    const int t = threadIdx.x;
    const int lane = t & 63, wid = t >> 6;           // wid 0..7

    if (blockIdx.x >= PASS1_BLOCKS) {
        // ================= GEMM: S16 = bf16(X @ W), 8 waves =================
        unsigned short* wt = (unsigned short*)shmem;            // [128][136]
        unsigned short* xt = (unsigned short*)(shmem + 34816);  // [64][136]
        const int row0 = (blockIdx.x - PASS1_BLOCKS) * 64;

        // stage W^T bf16: pure uint4 memcpy
        const uint4* WTg = (const uint4*)WT;
        uint4* wl = (uint4*)wt;
#pragma unroll
        for (int i = 0; i < 5; ++i) {
            int idx = t + 512 * i;                // 2176 uint4 total
            if (idx < 2176) wl[idx] = WTg[idx];
        }
        const float4* X4 = (const float4*)X;
#pragma unroll
        for (int i = 0; i < 4; ++i) {
            int idx4 = t + 512 * i;               // 2048 float4 total
            int r = idx4 >> 5, c4 = idx4 & 31;
            int gr = row0 + r;
            float4 v = make_float4(0.f, 0.f, 0.f, 0.f);
            if (gr < N_NODES) v = X4[gr * 32 + c4];
            ushort4 u = make_ushort4(f2bf(v.x), f2bf(v.y), f2bf(v.z), f2bf(v.w));
            *(ushort4*)&xt[r * 136 + c4 * 4] = u;
        }
        __syncthreads();

        const int m = lane & 15;
        const int q = lane >> 4;
        const int rbase = (wid >> 1) * 16;       // wave pair shares 16 rows
        const int h = wid & 1;                   // nt half: 0 -> nt 0..3, 1 -> 4..7

        f32x4 acc[4];
#pragma unroll
        for (int n4 = 0; n4 < 4; ++n4) acc[n4] = (f32x4){0.f, 0.f, 0.f, 0.f};
#pragma unroll
        for (int ks = 0; ks < 4; ++ks) {
            bf16x8 a = *(const bf16x8*)&xt[(rbase + m) * 136 + ks * 32 + q * 8];
#pragma unroll
            for (int n4 = 0; n4 < 4; ++n4) {
                int nt = h * 4 + n4;
                bf16x8 b = *(const bf16x8*)&wt[(nt * 16 + m) * 136 + ks * 32 + q * 8];
                acc[n4] = __builtin_amdgcn_mfma_f32_16x16x32_bf16(a, b, acc[n4], 0, 0, 0);
            }
        }
        __syncthreads();
#pragma unroll
        for (int n4 = 0; n4 < 4; ++n4) {
            int col = (h * 4 + n4) * 16 + m;
#pragma unroll
            for (int r = 0; r < 4; ++r) {
                int rl = rbase + q * 4 + r;
                xt[rl * 136 + col] = f2bf(acc[n4][r]);
            }
        }
        __syncthreads();
#pragma unroll
        for (int i = 0; i < 2; ++i) {
            int id = t + 512 * i;                 // 1024 uint4 total
            int r = id >> 4, c8 = (id & 15) * 8;
            int gr = row0 + r;
            if (gr < N_NODES)
                *(uint4*)&S16[gr * 128 + c8] = *(const uint4*)&xt[r * 136 + c8];
        }
    } else {
        // ================= PASS1: bucket multisplit, 8 waves =========
        int* bufx            = (int*)shmem;                         // [4096] 16KB
        int* bufw            = (int*)(shmem + 16384);               // [4096] 16KB
        unsigned short* bof  = (unsigned short*)(shmem + 32768);    // [4096] 8KB
        int* hist            = (int*)(shmem + 40960);               // [768]
        int* lcur            = (int*)(shmem + 44032);               // [768]
        int* bmg             = (int*)(shmem + 47104);               // [768]
        int* wsum            = (int*)(shmem + 50176);               // [8]
        int* wsum2           = (int*)(shmem + 50208);               // [4]
        const int base = blockIdx.x * CHUNK;

        hist[t] = 0;
        if (t < 256) hist[t + 512] = 0;
        __syncthreads();

        int rows[EPT];
        int bkt[EPT];
#pragma unroll
        for (int i = 0; i < EPT; ++i) {
            int e = base + t + 512 * i;
            rows[i] = (e < N_EDGES) ? ei[e] : -1;
            bkt[i] = (rows[i] >= 0) ? (rows[i] / BROWS) : -1;
            if (bkt[i] >= 0) atomicAdd(&hist[bkt[i]], 1);
        }
        __syncthreads();

        // exclusive scan of hist[768]: phase0 = entries 0..511 (8 waves),
        // phase1 = entries 512..767 (waves 0..3). Both wave-scans issued
        // before one barrier.
        int v0 = hist[t];
        int incl0 = v0;
#pragma unroll
        for (int off = 1; off < 64; off <<= 1) {
            int x = __shfl_up(incl0, off, 64);
            if (lane >= off) incl0 += x;
        }
        if (lane == 63) wsum[wid] = incl0;

        int v1 = 0, incl1 = 0;
        if (t < 256) {
            v1 = hist[512 + t];
            incl1 = v1;
#pragma unroll
            for (int off = 1; off < 64; off <<= 1) {
                int x = __shfl_up(incl1, off, 64);
                if (lane >= off) incl1 += x;
            }
            if (lane == 63) wsum2[wid] = incl1;
        }
        __syncthreads();

        int pre0 = 0, tot0 = 0;
#pragma unroll
        for (int w = 0; w < 8; ++w) {
            int x = wsum[w];
            if (w < wid) pre0 += x;
            tot0 += x;
        }
        int tot1 = wsum2[0] + wsum2[1] + wsum2[2] + wsum2[3];
        const int total = tot0 + tot1;
        int ex0 = incl0 - v0 + pre0;
        lcur[t] = ex0;
        int ex1 = 0;
        if (t < 256) {
            int pre1 = 0;
#pragma unroll
            for (int w = 0; w < 4; ++w)
                if (w < wid) pre1 += wsum2[w];
            ex1 = tot0 + incl1 - v1 + pre1;
            lcur[512 + t] = ex1;
        }

        // per-bucket global cursor reservation
        if (v0 > 0) {
            int gb = atomicAdd(&gcursor[t * CSTRIDE], v0);
            bmg[t] = t * SLOT + gb - ex0;
        }
        if (t < 256) {
            int b = 512 + t;
            if (b < NBUCKET && v1 > 0) {
                int gb = atomicAdd(&gcursor[b * CSTRIDE], v1);
                bmg[b] = b * SLOT + gb - ex1;
            }
        }
        __syncthreads();

        // local reorder into bucket-contiguous LDS
#pragma unroll
        for (int i = 0; i < EPT; ++i) {
            if (rows[i] >= 0) {
                int e = base + t + 512 * i;
                int col = ei[N_EDGES + e];
                float w = ew[e];
                int b = bkt[i];
                int lp = atomicAdd(&lcur[b], 1);
                int lrow = rows[i] - b * BROWS;     // 0..65
                bufx[lp] = (int)(((unsigned)lrow << 16) | (unsigned)col);
                bufw[lp] = __float_as_int(w);
                bof[lp] = (unsigned short)b;
            }
        }
        __syncthreads();

        // coalesced sweep: consecutive lp in same bucket -> consecutive gaddr
        for (int lp = t; lp < total; lp += 512) {
            int b = bof[lp];
            int g = bmg[b] + lp;
            if (g < (b + 1) * SLOT)
                staging[g] = make_int2(bufx[lp], bufw[lp]);   // overflow guard
        }
    }
}

// ---------------- K2: fused per-bucket sort + gather (R15 exact) ----------
__global__ __launch_bounds__(512) void sortgather_kernel(const unsigned short* __restrict__ S16,
                                                         const int* __restrict__ gcursor,
                                                         const int2* __restrict__ staging,
                                                         const float* __restrict__ bias,
                                                         float* __restrict__ out) {
    __shared__ int2 in0[SLOT];              // 12288 B
    __shared__ int2 in1[SLOT];              // 12288 B
    __shared__ int hist[128];               // entries >= BROWS stay 0
    __shared__ int exs[128];
    __shared__ int lcur[128];
    __shared__ int wsum[2];
    const int t = threadIdx.x;
    const int b = blockIdx.x;
    const int lane = t & 63;
    int cnt = gcursor[b * CSTRIDE];
    if (cnt > SLOT) cnt = SLOT;

    if (t < 128) hist[t] = 0;
    __syncthreads();

    for (int i = t; i < cnt; i += 512) {
        int2 v = staging[b * SLOT + i];
        in0[i] = v;
        atomicAdd(&hist[((unsigned)v.x >> 16) & 127u], 1);
    }
    __syncthreads();

    // scan hist[128] using threads 0..127
    int v = 0, incl = 0;
    if (t < 128) {
        v = hist[t];
        incl = v;
#pragma unroll
        for (int off = 1; off < 64; off <<= 1) {
            int x = __shfl_up(incl, off, 64);
            if (lane >= off) incl += x;
        }
        if (lane == 63) wsum[t >> 6] = incl;
    }
    __syncthreads();
    if (t < 128) {
        int pre = (t >= 64) ? wsum[0] : 0;
        int ex = incl - v + pre;
        exs[t] = ex;
        lcur[t] = ex;
    }
    __syncthreads();

    // sort payload directly into in1 (row-contiguous)
    for (int i = t; i < cnt; i += 512) {
        int2 e = in0[i];
        int lr = (int)(((unsigned)e.x >> 16) & 127u);
        int p = atomicAdd(&lcur[lr], 1);
        in1[p] = e;
    }
    __syncthreads();

    // gather
    const int wv = t >> 6;                   // 0..7
    const int sub = lane >> 4;               // 0..3 edge sub-streams
    const int q = lane & 15;                 // owns dims q*8..q*8+7
    const uint4* S4 = (const uint4*)S16;     // row stride: 16 uint4
    const float4* bias4 = (const float4*)bias;
    const float4 b0 = bias4[q * 2];
    const float4 b1 = bias4[q * 2 + 1];

    for (int rr = wv; rr < BROWS; rr += 8) {
        const int beg = exs[rr];
        const int end = beg + hist[rr];
        float acc[8];
#pragma unroll
        for (int i = 0; i < 8; ++i) acc[i] = 0.f;

        int p = beg + sub;
        // 2-deep pipeline: two edges' loads in flight before their FMAs
        for (; p + 4 < end; p += 8) {
            int2 cw0 = in1[p];
            int2 cw1 = in1[p + 4];
            uint4 v0 = S4[(cw0.x & 0xFFFF) * 16 + q];
            uint4 v1 = S4[(cw1.x & 0xFFFF) * 16 + q];
            float w0 = __int_as_float(cw0.y);
            float w1 = __int_as_float(cw1.y);
            fma8(acc, v0, w0);
            fma8(acc, v1, w1);
        }
        if (p < end) {
            int2 cw = in1[p];
            uint4 v2 = S4[(cw.x & 0xFFFF) * 16 + q];
            float w = __int_as_float(cw.y);
            fma8(acc, v2, w);
        }
#pragma unroll
        for (int i = 0; i < 8; ++i) acc[i] += __shfl_xor(acc[i], 16, 64);
#pragma unroll
        for (int i = 0; i < 8; ++i) acc[i] += __shfl_xor(acc[i], 32, 64);

        int gr = b * BROWS + rr;
        if (sub == 0 && gr < N_NODES) {
            float4 o0 = make_float4(acc[0] + b0.x, acc[1] + b0.y,
                                    acc[2] + b0.z, acc[3] + b0.w);
            float4 o1 = make_float4(acc[4] + b1.x, acc[5] + b1.y,
                                    acc[6] + b1.z, acc[7] + b1.w);
            ((float4*)out)[gr * 32 + q * 2] = o0;
            ((float4*)out)[gr * 32 + q * 2 + 1] = o1;
        }
    }
}

extern "C" void kernel_launch(void* const* d_in, const int* in_sizes, int n_in,
                              void* d_out, int out_size, void* d_ws, size_t ws_size,
                              hipStream_t stream) {
    const float* X    = (const float*)d_in[0];
    const int*   ei   = (const int*)d_in[1];
    const float* ew   = (const float*)d_in[2];
    const float* W    = (const float*)d_in[3];
    const float* bias = (const float*)d_in[4];
    float* out = (float*)d_out;

    char* ws = (char*)d_ws;
    unsigned short* S16 = (unsigned short*)(ws);
    int2* staging = (int2*)(ws + 12800000);
    int*  gcursor = (int*)(ws + 22114304);
    unsigned short* WT16 = (unsigned short*)(ws + 22162816);

    wprep_kernel<<<64, 256, 0, stream>>>(W, WT16, gcursor);
    fused_kernel<<<GEMM_BLOCKS + PASS1_BLOCKS, 512, 0, stream>>>(X, WT16, S16, ei, ew,
                                                                 gcursor, staging);
    sortgather_kernel<<<NBUCKET, 512, 0, stream>>>(S16, gcursor, staging, bias, out);
}